// Round 1
// baseline (1368.918 us; speedup 1.0000x reference)
//
#include <hip/hip_runtime.h>
#include <cstdint>
#include <cstddef>

#define B_   32
#define T_   128
#define H_   1024
#define V_   32000
#define NBLK 256
#define NTHR 256
#define JB   4        // hidden columns per block -> 12 W_hh rows

// Dynamic LDS layout (floats):
//   Wl  [12][1024]           12288
//   red [256][100]           25600   (row stride 100 floats = 400B, 400%128=16 -> bank-quad walk)
//   ghl [12][32]               384
#define LDS_WL_OFF   0
#define LDS_RED_OFF  (12*1024)
#define LDS_GHL_OFF  (12*1024 + 256*100)
#define LDS_FLOATS   (12*1024 + 256*100 + 12*32)

__global__ __launch_bounds__(NTHR) void gru_step(
    const float* __restrict__ Whh,   // (3072,1024)
    const float* __restrict__ bhh,   // (3072)
    const float* __restrict__ Wih,   // (3072,32000)
    const float* __restrict__ bih,   // (3072)
    const int*   __restrict__ xs,    // (B,T)
    const float* __restrict__ hcur,  // (B,H)   (unread when t==0)
    float*       __restrict__ hnxt,  // (B,H)
    float*       __restrict__ outp,  // (B,T,H)
    float*       __restrict__ hidout,// (B,H) final hidden or nullptr
    int t)
{
    extern __shared__ float lds[];
    float* Wl  = lds + LDS_WL_OFF;
    float* red = lds + LDS_RED_OFF;
    float* ghl = lds + LDS_GHL_OFF;

    const int tid = threadIdx.x;
    const int j0  = (int)blockIdx.x * JB;

    // ---- gate-phase prefetch (threads 0..127): jj = tid&3, b = tid>>2 ----
    // Issue the scattered W_ih gather loads EARLY so HBM latency hides under
    // the LDS fill + main FMA loop.
    float xg0 = 0.f, xg1 = 0.f, xg2 = 0.f, hold = 0.f;
    const int gjj = tid & 3;
    const int gb  = tid >> 2;
    if (tid < 128) {
        const int tok = xs[gb * T_ + t];
        xg0 = Wih[(size_t)(0*H_ + j0 + gjj) * V_ + tok] + bih[0*H_ + j0 + gjj];
        xg1 = Wih[(size_t)(1*H_ + j0 + gjj) * V_ + tok] + bih[1*H_ + j0 + gjj];
        xg2 = Wih[(size_t)(2*H_ + j0 + gjj) * V_ + tok] + bih[2*H_ + j0 + gjj];
        if (t > 0) hold = hcur[(size_t)gb * H_ + j0 + gjj];
    }

    // ---- stage W_hh tile (12 rows x 1024) into LDS, float4 coalesced ----
    #pragma unroll
    for (int i = 0; i < 12; ++i) {
        const int idx = i * NTHR + tid;   // float4 index, 0..3071
        const int r   = idx >> 8;         // row 0..11 (256 float4 per row)
        const int kv  = idx & 255;
        const int g   = r >> 2, jj = r & 3;
        const float4 v = ((const float4*)(Whh + (size_t)(g*H_ + j0 + jj) * H_))[kv];
        ((float4*)(Wl + r * H_))[kv] = v;
    }
    __syncthreads();

    // ---- main GEMM phase: thread = (bq = tid>>6 in 0..3, kq = tid&63) ----
    // b-tile = 8 (b = bq*8..+7), k-slices: k = kq*4 + c*256, c = 0..3
    const int kq = tid & 63;
    const int bq = tid >> 6;

    float acc[12][8];
    #pragma unroll
    for (int r = 0; r < 12; ++r)
        #pragma unroll
        for (int bb = 0; bb < 8; ++bb) acc[r][bb] = 0.f;

    if (t > 0) {
        #pragma unroll
        for (int c = 0; c < 4; ++c) {
            const int k = kq * 4 + c * 256;
            float4 h4[8];
            #pragma unroll
            for (int bb = 0; bb < 8; ++bb)
                h4[bb] = *(const float4*)(hcur + (size_t)(bq*8 + bb) * H_ + k);
            float4 w4[12];
            #pragma unroll
            for (int r = 0; r < 12; ++r)
                w4[r] = *(const float4*)(Wl + r * H_ + k);
            #pragma unroll
            for (int r = 0; r < 12; ++r) {
                #pragma unroll
                for (int bb = 0; bb < 8; ++bb) {
                    acc[r][bb] += w4[r].x * h4[bb].x;
                    acc[r][bb] += w4[r].y * h4[bb].y;
                    acc[r][bb] += w4[r].z * h4[bb].z;
                    acc[r][bb] += w4[r].w * h4[bb].w;
                }
            }
        }
    }

    // ---- spill partials to LDS: red[tid][a4*4 + e], a4 = r*2 + (bb>>2) ----
    #pragma unroll
    for (int r = 0; r < 12; ++r) {
        #pragma unroll
        for (int bh = 0; bh < 2; ++bh) {
            const float4 v = make_float4(acc[r][bh*4+0], acc[r][bh*4+1],
                                         acc[r][bh*4+2], acc[r][bh*4+3]);
            *(float4*)(red + (size_t)tid * 100 + (r*2 + bh) * 4) = v;
        }
    }
    __syncthreads();

    // ---- reduce across 64 k-slices: 96 threads, one float4 (4 b's) each ----
    if (tid < 96) {
        const int r   = tid >> 3;        // 0..11
        const int bq2 = (tid >> 1) & 3;  // 0..3
        const int bh  = tid & 1;         // 0..1
        const int a4  = r*2 + bh;
        float4 s = make_float4(0.f, 0.f, 0.f, 0.f);
        #pragma unroll 8
        for (int q = 0; q < 64; ++q) {
            const float4 v = *(const float4*)(red + (size_t)(bq2*64 + q) * 100 + a4 * 4);
            s.x += v.x; s.y += v.y; s.z += v.z; s.w += v.w;
        }
        const int g = r >> 2, jj = r & 3;
        const float bias = bhh[g*H_ + j0 + jj];
        s.x += bias; s.y += bias; s.z += bias; s.w += bias;
        *(float4*)(ghl + r * 32 + bq2*8 + bh*4) = s;   // ghl[r][b]
    }
    __syncthreads();

    // ---- gate math + writes: threads 0..127, (jj = tid&3, b = tid>>2) ----
    if (tid < 128) {
        const float hr = ghl[(0*4 + gjj) * 32 + gb];
        const float hz = ghl[(1*4 + gjj) * 32 + gb];
        const float hn = ghl[(2*4 + gjj) * 32 + gb];
        const float rg = 1.f / (1.f + __expf(-(xg0 + hr)));
        const float zg = 1.f / (1.f + __expf(-(xg1 + hz)));
        const float tn = xg2 + rg * hn;
        const float e  = __expf(-2.f * fabsf(tn));
        const float m  = (1.f - e) / (1.f + e);
        const float ng = copysignf(m, tn);          // tanh(tn), inf-safe
        const float hnew = (1.f - zg) * ng + zg * hold;

        hnxt[(size_t)gb * H_ + j0 + gjj] = hnew;
        outp[((size_t)gb * T_ + t) * H_ + j0 + gjj] = hnew;
        if (hidout) hidout[(size_t)gb * H_ + j0 + gjj] = hnew;
    }
}

extern "C" void kernel_launch(void* const* d_in, const int* in_sizes, int n_in,
                              void* d_out, int out_size, void* d_ws, size_t ws_size,
                              hipStream_t stream) {
    const int*   xs  = (const int*)  d_in[0];
    const float* Wih = (const float*)d_in[1];
    const float* Whh = (const float*)d_in[2];
    const float* bih = (const float*)d_in[3];
    const float* bhh = (const float*)d_in[4];

    float* outp = (float*)d_out;
    float* hid  = outp + (size_t)B_ * T_ * H_;   // final hidden region

    float* h0 = (float*)d_ws;                    // (B,H) ping
    float* h1 = h0 + (size_t)B_ * H_;            // (B,H) pong

    const size_t LDSB = (size_t)LDS_FLOATS * sizeof(float);   // 153088 B
    (void)hipFuncSetAttribute((const void*)gru_step,
                              hipFuncAttributeMaxDynamicSharedMemorySize,
                              (int)LDSB);

    float* hb[2] = { h0, h1 };
    for (int t = 0; t < T_; ++t) {
        gru_step<<<NBLK, NTHR, LDSB, stream>>>(
            Whh, bhh, Wih, bih, xs,
            hb[t & 1], hb[(t + 1) & 1],
            outp, (t == T_ - 1) ? hid : nullptr, t);
    }
    (void)in_sizes; (void)n_in; (void)out_size; (void)ws_size;
}